// Round 10
// baseline (1460.211 us; speedup 1.0000x reference)
//
#include <hip/hip_runtime.h>

#define HH 128
#define GG 64
#define EPS 1e-5f

// monotonic float <-> uint mapping for atomicMax on floats of any sign
__device__ __forceinline__ unsigned femax_enc(float f) {
    unsigned u = __float_as_uint(f);
    return (u & 0x80000000u) ? ~u : (u | 0x80000000u);
}
__device__ __forceinline__ float femax_dec(unsigned u) {
    return (u & 0x80000000u) ? __uint_as_float(u & 0x7FFFFFFFu) : __uint_as_float(~u);
}

// ---------------- CSR build ----------------
__global__ void k_count(const int* __restrict__ dst, int* __restrict__ cnt, int E) {
    int i = blockIdx.x * blockDim.x + threadIdx.x;
    if (i < E) atomicAdd(&cnt[dst[i]], 1);
}

__global__ __launch_bounds__(512) void k_scanA(const int* __restrict__ cnt, int* __restrict__ tmp,
                                               int* __restrict__ bsum, int n) {
    __shared__ int s[512];
    int t = threadIdx.x;
    int i = blockIdx.x * 512 + t;
    s[t] = (i < n) ? cnt[i] : 0;
    __syncthreads();
    for (int o = 1; o < 512; o <<= 1) {
        int u = (t >= o) ? s[t - o] : 0;
        __syncthreads();
        s[t] += u;
        __syncthreads();
    }
    if (i < n) tmp[i] = s[t];
    if (t == 511) bsum[blockIdx.x] = s[511];
}

__global__ __launch_bounds__(512) void k_scanB(int* __restrict__ bsum, int nb) {
    __shared__ int s[512];
    int t = threadIdx.x;
    s[t] = (t < nb) ? bsum[t] : 0;
    __syncthreads();
    for (int o = 1; o < 512; o <<= 1) {
        int u = (t >= o) ? s[t - o] : 0;
        __syncthreads();
        s[t] += u;
        __syncthreads();
    }
    if (t < nb) bsum[t] = s[t];
}

// rowptr + dinv fused
__global__ void k_scanC(const int* __restrict__ tmp, const int* __restrict__ bsum,
                        const int* __restrict__ cnt, int* __restrict__ rowptr,
                        float* __restrict__ dinv, int n) {
    int i = blockIdx.x * blockDim.x + threadIdx.x;
    if (i < n) {
        int b = i >> 9;
        int off = (b > 0) ? bsum[b - 1] : 0;
        rowptr[i + 1] = tmp[i] + off;
        if (i == 0) rowptr[0] = 0;
        dinv[i] = rsqrtf((float)(cnt[i] + 1));
    }
}

// fill packed (col, norm) pairs
__global__ void k_fill(const int* __restrict__ src, const int* __restrict__ dst,
                       const int* __restrict__ rowptr, int* __restrict__ cursor,
                       const float* __restrict__ dinv, int2* __restrict__ epk, int E) {
    int e = blockIdx.x * blockDim.x + threadIdx.x;
    if (e < E) {
        int s0 = src[e], d0 = dst[e];
        int p = atomicAdd(&cursor[d0], 1);
        int idx = rowptr[d0] + p;
        epk[idx] = make_int2(s0, __float_as_int(dinv[s0] * dinv[d0]));
    }
}

// ---------------- GEMM with fused BN-apply staging ----------------
// Layout = R6 (proven): thread owns 8 CONSECUTIVE cols tx8 (float4 W reads + float4 stores).
// Kept from R7: 16-row double-buffered W chunks with register prefetch before the barrier.
// BNIN==0: stage Ain raw.  BNIN==1: stage h = relu(bn(Ain)) (+res); h in place to Aio.
// ACT==0: C = staged @ W.  ACT==1: apre[r] = tanh(staged@W + b1) @ w2 + b2, track max.
#define FMA_ROW(i, a)                       \
    acc[i][0] = fmaf(a, w0.x, acc[i][0]);   \
    acc[i][1] = fmaf(a, w0.y, acc[i][1]);   \
    acc[i][2] = fmaf(a, w0.z, acc[i][2]);   \
    acc[i][3] = fmaf(a, w0.w, acc[i][3]);   \
    acc[i][4] = fmaf(a, w1.x, acc[i][4]);   \
    acc[i][5] = fmaf(a, w1.y, acc[i][5]);   \
    acc[i][6] = fmaf(a, w1.z, acc[i][6]);   \
    acc[i][7] = fmaf(a, w1.w, acc[i][7]);

template <int BNIN, int ACT>
__global__ __launch_bounds__(256, 3) void k_gemm(const float* __restrict__ Ain, float* __restrict__ Aio,
                                                 const float* __restrict__ res,
                                                 const float* __restrict__ csum, const float* __restrict__ csq,
                                                 const float* __restrict__ bng, const float* __restrict__ bnb,
                                                 const float* __restrict__ W, const float* __restrict__ bias,
                                                 float* __restrict__ C, const float* __restrict__ w2,
                                                 const float* __restrict__ b2, unsigned* __restrict__ gmax,
                                                 int n) {
    __shared__ float hl[64][132];      // 33.8 KB; pad 132: A-col reads spread banks
    __shared__ float Ws[2][16][128];   // 16.4 KB dbuf W chunk -> 50.2 KB total, 3 blocks/CU
    int tb = blockIdx.x * 64;
    int t = threadIdx.x;
    int rows = n - tb; if (rows > 64) rows = 64;
    int c4 = (t & 31) << 2;
    int wr = t >> 5;                   // W-stage row 0..7 (and +8)

    float A0c = 0.f, A1c = 0.f, A2c = 0.f, A3c = 0.f;
    float B0c = 0.f, B1c = 0.f, B2c = 0.f, B3c = 0.f;
    if (BNIN) {
        float4 cs = *(const float4*)&csum[c4];
        float4 cq = *(const float4*)&csq[c4];
        float4 gg = *(const float4*)&bng[c4];
        float4 bb = *(const float4*)&bnb[c4];
        float inv_n = 1.0f / (float)n;
        float m0 = cs.x * inv_n, m1 = cs.y * inv_n, m2 = cs.z * inv_n, m3 = cs.w * inv_n;
        A0c = rsqrtf(cq.x * inv_n - m0 * m0 + EPS) * gg.x;
        A1c = rsqrtf(cq.y * inv_n - m1 * m1 + EPS) * gg.y;
        A2c = rsqrtf(cq.z * inv_n - m2 * m2 + EPS) * gg.z;
        A3c = rsqrtf(cq.w * inv_n - m3 * m3 + EPS) * gg.w;
        B0c = bb.x - m0 * A0c; B1c = bb.y - m1 * A1c; B2c = bb.z - m2 * A2c; B3c = bb.w - m3 * A3c;
    }
    // W chunk-0 prefetch (regs), issued before A staging so latency overlaps it
    float4 wp0 = *(const float4*)&W[(size_t)wr * HH + c4];
    float4 wp1 = *(const float4*)&W[(size_t)(wr + 8) * HH + c4];

    for (int idx = t; idx < 64 * 32; idx += 256) {
        int r = idx >> 5;
        if (r < rows) {
            size_t go = (size_t)(tb + r) * HH + c4;
            float4 v = *(const float4*)&Ain[go];
            if (BNIN) {
                v.x = fmaxf(fmaf(v.x, A0c, B0c), 0.f);
                v.y = fmaxf(fmaf(v.y, A1c, B1c), 0.f);
                v.z = fmaxf(fmaf(v.z, A2c, B2c), 0.f);
                v.w = fmaxf(fmaf(v.w, A3c, B3c), 0.f);
                if (res) {
                    float4 rv = *(const float4*)&res[go];
                    v.x += rv.x; v.y += rv.y; v.z += rv.z; v.w += rv.w;
                }
                *(float4*)&Aio[go] = v;     // in-place h write (each elem touched once)
            }
            *(float4*)&hl[r][c4] = v;
        }
    }
    *(float4*)&Ws[0][wr][c4] = wp0;
    *(float4*)&Ws[0][wr + 8][c4] = wp1;

    int tx = t & 15;       // owns cols tx8 .. tx8+7 (consecutive -> float4 stores)
    int ty = t >> 4;       // owns rows ty + 16*i
    int tx8 = tx << 3;
    float acc[4][8] = {};
    for (int kc = 0; kc < 8; ++kc) {
        if (kc < 7) {       // issue next W chunk loads before the barrier; land during compute
            wp0 = *(const float4*)&W[(size_t)((kc + 1) * 16 + wr) * HH + c4];
            wp1 = *(const float4*)&W[(size_t)((kc + 1) * 16 + wr + 8) * HH + c4];
        }
        __syncthreads();   // Ws[kc&1] writes visible (and hl on kc=0)
        const float (*Wc)[128] = Ws[kc & 1];
        int kb = kc * 16;
#pragma unroll
        for (int k4 = 0; k4 < 16; k4 += 4) {
            float a0v[4], a1v[4], a2v[4], a3v[4];
            *(float4*)a0v = *(const float4*)&hl[ty][kb + k4];
            *(float4*)a1v = *(const float4*)&hl[ty + 16][kb + k4];
            *(float4*)a2v = *(const float4*)&hl[ty + 32][kb + k4];
            *(float4*)a3v = *(const float4*)&hl[ty + 48][kb + k4];
#pragma unroll
            for (int j = 0; j < 4; ++j) {
                float4 w0 = *(const float4*)&Wc[k4 + j][tx8];
                float4 w1 = *(const float4*)&Wc[k4 + j][tx8 + 4];
                FMA_ROW(0, a0v[j])
                FMA_ROW(1, a1v[j])
                FMA_ROW(2, a2v[j])
                FMA_ROW(3, a3v[j])
            }
        }
        if (kc < 7) {       // write prefetched chunk into the other buffer
            *(float4*)&Ws[(kc + 1) & 1][wr][c4] = wp0;
            *(float4*)&Ws[(kc + 1) & 1][wr + 8][c4] = wp1;
        }
    }
    if (ACT == 0) {
#pragma unroll
        for (int i = 0; i < 4; ++i) {
            int r = tb + ty + 16 * i;
            if (r < n) {
                float4 o0 = {acc[i][0], acc[i][1], acc[i][2], acc[i][3]};
                float4 o1 = {acc[i][4], acc[i][5], acc[i][6], acc[i][7]};
                *(float4*)&C[(size_t)r * HH + tx8] = o0;
                *(float4*)&C[(size_t)r * HH + tx8 + 4] = o1;
            }
        }
    } else {
        // fused attention GEMV: apre[r] = sum_c tanh(acc+b1[c]) * w2[c] + b2; track global max
        float b1v[8], w2v[8];
#pragma unroll
        for (int j = 0; j < 8; ++j) { b1v[j] = bias[tx8 + j]; w2v[j] = w2[tx8 + j]; }
        float b2s = b2[0];
        float lmax = -3.4e38f;
#pragma unroll
        for (int i = 0; i < 4; ++i) {
            float s = 0.f;
#pragma unroll
            for (int j = 0; j < 8; ++j)
                s = fmaf(tanhf(acc[i][j] + b1v[j]), w2v[j], s);
            s += __shfl_xor(s, 1);
            s += __shfl_xor(s, 2);
            s += __shfl_xor(s, 4);
            s += __shfl_xor(s, 8);
            int r = tb + ty + 16 * i;
            float val = s + b2s;
            if (r < n) {
                lmax = fmaxf(lmax, val);
                if (tx == 0) C[r] = val;
            }
        }
        lmax = fmaxf(lmax, __shfl_xor(lmax, 16));
        lmax = fmaxf(lmax, __shfl_xor(lmax, 32));
        __shared__ float wm[4];
        if ((t & 63) == 0) wm[t >> 6] = lmax;
        __syncthreads();
        if (t == 0) {
            float m = fmaxf(fmaxf(wm[0], wm[1]), fmaxf(wm[2], wm[3]));
            atomicMax(gmax, femax_enc(m));
        }
    }
}

// ---------------- Aggregation ----------------
#define AGG_FMA(vv, ww)                                           \
    acc.x = fmaf(vv.x, ww, acc.x); acc.y = fmaf(vv.y, ww, acc.y); \
    acc.z = fmaf(vv.z, ww, acc.z); acc.w = fmaf(vv.w, ww, acc.w);

__global__ __launch_bounds__(256) void k_agg(const float* __restrict__ z, const int* __restrict__ rowptr,
                                             const int2* __restrict__ epk, const float* __restrict__ dinv,
                                             const float* __restrict__ bias, float* __restrict__ agg, int n) {
    int wid = (int)((blockIdx.x * (size_t)blockDim.x + threadIdx.x) >> 6);
    if (wid >= n) return;
    int lane = threadIdx.x & 63;
    int half = lane >> 5;
    int c0 = (lane & 31) << 2;
    int beg = rowptr[wid], end = rowptr[wid + 1];
    float4 acc = {0.f, 0.f, 0.f, 0.f};
    if (half == 0) {
        float di = dinv[wid];
        float ws = di * di;
        float4 zs = *(const float4*)&z[(size_t)wid * HH + c0];
        acc.x = zs.x * ws; acc.y = zs.y * ws; acc.z = zs.z * ws; acc.w = zs.w * ws;
    }
    for (int e = beg + half; e < end; e += 16) {
        int2 p[8];
        float w[8];
#pragma unroll
        for (int j = 0; j < 8; ++j) {
            int idx = e + 2 * j;
            bool valid = idx < end;
            p[j] = epk[valid ? idx : beg];
            w[j] = valid ? __int_as_float(p[j].y) : 0.f;
        }
        float4 v[8];
#pragma unroll
        for (int j = 0; j < 8; ++j)
            v[j] = *(const float4*)&z[(size_t)p[j].x * HH + c0];
#pragma unroll
        for (int j = 0; j < 8; ++j) { AGG_FMA(v[j], w[j]) }
    }
    acc.x += __shfl_xor(acc.x, 32);
    acc.y += __shfl_xor(acc.y, 32);
    acc.z += __shfl_xor(acc.z, 32);
    acc.w += __shfl_xor(acc.w, 32);
    if (half == 0) {
        float4 b4 = *(const float4*)&bias[c0];
        acc.x += b4.x; acc.y += b4.y; acc.z += b4.z; acc.w += b4.w;
        *(float4*)&agg[(size_t)wid * HH + c0] = acc;
    }
}

// ---------------- BatchNorm stats ----------------
__global__ __launch_bounds__(256) void k_bnstats(const float* __restrict__ agg, float* __restrict__ colsum,
                                                 float* __restrict__ colsq, int n) {
    int t = threadIdx.x;
    int col = t & 127, sub = t >> 7;
    int rpb = (n + gridDim.x - 1) / gridDim.x;
    int r0 = blockIdx.x * rpb;
    int r1 = r0 + rpb; if (r1 > n) r1 = n;
    float s = 0.f, q = 0.f;
    for (int r = r0 + sub; r < r1; r += 2) {
        float v = agg[(size_t)r * HH + col];
        s += v;
        q = fmaf(v, v, q);
    }
    __shared__ float ls[256], lq[256];
    ls[t] = s; lq[t] = q;
    __syncthreads();
    if (t < 128) {
        atomicAdd(&colsum[col], ls[t] + ls[t + 128]);
        atomicAdd(&colsq[col], lq[t] + lq[t + 128]);
    }
}

// ---------------- Pooling (batch sorted) + global exp-sum ----------------
__global__ __launch_bounds__(256) void k_pool(const float* __restrict__ h, const float* __restrict__ apre,
                                              const int* __restrict__ batch, const unsigned* __restrict__ gmax,
                                              float* __restrict__ pooled, float* __restrict__ counts,
                                              float* __restrict__ Sglob, int n) {
    float M = femax_dec(*gmax);
    int t = threadIdx.x;
    int col = t & 127, sub = t >> 7;
    int rpb = (n + gridDim.x - 1) / gridDim.x;
    int r0 = blockIdx.x * rpb;
    int r1 = r0 + rpb; if (r1 > n) r1 = n;
    float acc = 0.f, cntf = 0.f, es = 0.f;
    int cur = -1;
    for (int r = r0 + sub; r < r1; r += 2) {
        int g = batch[r];
        if (g != cur) {
            if (cur >= 0) {
                atomicAdd(&pooled[cur * HH + col], acc);
                if (col == 0) atomicAdd(&counts[cur], cntf);
            }
            cur = g; acc = 0.f; cntf = 0.f;
        }
        float s = expf(apre[r] - M);
        acc = fmaf(h[(size_t)r * HH + col], s, acc);
        cntf += 1.0f;
        if (col == 0) es += s;
    }
    if (cur >= 0) {
        atomicAdd(&pooled[cur * HH + col], acc);
        if (col == 0) atomicAdd(&counts[cur], cntf);
    }
    if (col == 0 && es != 0.f) atomicAdd(Sglob, es);
}

// ---------------- Final MLP ----------------
__global__ __launch_bounds__(128) void k_mlp(const float* __restrict__ pooled, const float* __restrict__ counts,
                                             const float* __restrict__ Sglob, const float* __restrict__ W1,
                                             const float* __restrict__ b1, const float* __restrict__ W2,
                                             const float* __restrict__ b2, float* __restrict__ out) {
    int g = blockIdx.x;
    int t = threadIdx.x;
    __shared__ float p[128], t1[128];
    float S = Sglob[0];
    float c = fmaxf(counts[g], 1.0f);
    p[t] = pooled[g * HH + t] / (S * c);
    __syncthreads();
    float acc = b1[t];
    for (int k = 0; k < 128; ++k) acc = fmaf(p[k], W1[k * HH + t], acc);
    t1[t] = fmaxf(acc, 0.f);
    __syncthreads();
    float acc2 = b2[t];
    for (int j = 0; j < 128; ++j) acc2 = fmaf(t1[j], W2[j * HH + t], acc2);
    out[g * HH + t] = acc2;
}

extern "C" void kernel_launch(void* const* d_in, const int* in_sizes, int n_in,
                              void* d_out, int out_size, void* d_ws, size_t ws_size,
                              hipStream_t stream) {
    const float* x       = (const float*)d_in[0];
    const int*   ei      = (const int*)d_in[1];
    const int*   batch   = (const int*)d_in[2];
    const float* conv_w  = (const float*)d_in[3];
    const float* conv_b  = (const float*)d_in[4];
    const float* bn_g    = (const float*)d_in[5];
    const float* bn_b    = (const float*)d_in[6];
    const float* attn_w1 = (const float*)d_in[7];
    const float* attn_b1 = (const float*)d_in[8];
    const float* attn_w2 = (const float*)d_in[9];
    const float* attn_b2 = (const float*)d_in[10];
    const float* proj_w1 = (const float*)d_in[11];
    const float* proj_b1 = (const float*)d_in[12];
    const float* proj_w2 = (const float*)d_in[13];
    const float* proj_b2 = (const float*)d_in[14];

    const int E = in_sizes[1] / 2;
    const int n = in_sizes[2];
    const int* srcp = ei;
    const int* dstp = ei + E;

    // ---- workspace layout ----
    char* base = (char*)d_ws;
    size_t off = 0;
    auto alloc = [&](size_t bytes) -> char* {
        char* p = base + off;
        off = (off + bytes + 511) & ~(size_t)511;
        return p;
    };
    int*   cntcur  = (int*)alloc((size_t)2 * n * 4);     // cnt | cursor (one memset)
    int*   cnt     = cntcur;
    int*   cursor  = cntcur + n;
    int*   rowptr  = (int*)alloc((size_t)(n + 1) * 4);
    int*   tmp     = (int*)alloc((size_t)n * 4);
    int*   bsum    = (int*)alloc(512 * 4);
    float* dinv    = (float*)alloc((size_t)n * 4);
    int2*  epk     = (int2*)alloc((size_t)E * 8);
    float* z       = (float*)alloc((size_t)n * HH * 4);
    float* aggA    = (float*)alloc((size_t)n * HH * 4);
    float* aggB    = (float*)alloc((size_t)n * HH * 4);
    float* apre    = (float*)alloc((size_t)n * 4);
    // zero arena: colstats(3*256 floats) | gmax(1) | S(1) | pad->1024 | pooled(8192) | counts(64)
    float* zarena  = (float*)alloc((size_t)(1024 + GG * HH + GG) * 4);
    float* cs0 = zarena;            float* cq0 = zarena + 128;
    float* cs1 = zarena + 256;      float* cq1 = zarena + 384;
    float* cs2 = zarena + 512;      float* cq2 = zarena + 640;
    unsigned* gmaxu = (unsigned*)(zarena + 768);
    float* Sglob  = zarena + 769;
    float* pooled = zarena + 1024;
    float* counts = zarena + 1024 + GG * HH;
    const size_t zbytes = (size_t)(1024 + GG * HH + GG) * 4;

    const int eGrid    = (E + 255) / 256;
    const int nGrid    = (n + 255) / 256;
    const int nbScan   = (n + 511) / 512;
    const int gemmGrid = (n + 63) / 64;
    const int waveGrid = (n + 3) / 4;

    // ---- zero accumulators + CSR build ----
    hipMemsetAsync(zarena, 0, zbytes, stream);
    hipMemsetAsync(cntcur, 0, (size_t)2 * n * 4, stream);
    k_count<<<eGrid, 256, 0, stream>>>(dstp, cnt, E);
    k_scanA<<<nbScan, 512, 0, stream>>>(cnt, tmp, bsum, n);
    k_scanB<<<1, 512, 0, stream>>>(bsum, nbScan);
    k_scanC<<<nGrid, 256, 0, stream>>>(tmp, bsum, cnt, rowptr, dinv, n);
    k_fill<<<eGrid, 256, 0, stream>>>(srcp, dstp, rowptr, cursor, dinv, epk, E);

    // ---- layer 0 ----
    k_gemm<0, 0><<<gemmGrid, 256, 0, stream>>>(x, nullptr, nullptr, nullptr, nullptr, nullptr, nullptr,
                                               conv_w, nullptr, z, nullptr, nullptr, nullptr, n);
    k_agg<<<waveGrid, 256, 0, stream>>>(z, rowptr, epk, dinv, conv_b, aggA, n);
    k_bnstats<<<1024, 256, 0, stream>>>(aggA, cs0, cq0, n);

    // ---- layer 1 (BN0 fused into staging; h1 -> aggA in place) ----
    k_gemm<1, 0><<<gemmGrid, 256, 0, stream>>>(aggA, aggA, nullptr, cs0, cq0, bn_g, bn_b,
                                               conv_w + (size_t)HH * HH, nullptr, z, nullptr, nullptr,
                                               nullptr, n);
    k_agg<<<waveGrid, 256, 0, stream>>>(z, rowptr, epk, dinv, conv_b + HH, aggB, n);
    k_bnstats<<<1024, 256, 0, stream>>>(aggB, cs1, cq1, n);

    // ---- layer 2 (BN1 fused; res=h1(aggA); h2 -> aggB in place) ----
    k_gemm<1, 0><<<gemmGrid, 256, 0, stream>>>(aggB, aggB, aggA, cs1, cq1, bn_g + HH, bn_b + HH,
                                               conv_w + (size_t)2 * HH * HH, nullptr, z, nullptr, nullptr,
                                               nullptr, n);
    k_agg<<<waveGrid, 256, 0, stream>>>(z, rowptr, epk, dinv, conv_b + 2 * HH, aggA, n);
    k_bnstats<<<1024, 256, 0, stream>>>(aggA, cs2, cq2, n);

    // ---- attention gemm (BN2 fused; res=h2(aggB); h3 -> aggA in place; GEMV+max epilogue) ----
    k_gemm<1, 1><<<gemmGrid, 256, 0, stream>>>(aggA, aggA, aggB, cs2, cq2, bn_g + 2 * HH, bn_b + 2 * HH,
                                               attn_w1, attn_b1, apre, attn_w2, attn_b2, gmaxu, n);

    // ---- pooling (+ global exp-sum) + MLP ----
    k_pool<<<1024, 256, 0, stream>>>(aggA, apre, batch, gmaxu, pooled, counts, Sglob, n);
    k_mlp<<<GG, 128, 0, stream>>>(pooled, counts, Sglob, proj_w1, proj_b1, proj_w2, proj_b2,
                                  (float*)d_out);
}

// Round 12
// 1124.029 us; speedup vs baseline: 1.2991x; 1.2991x over previous
//
#include <hip/hip_runtime.h>

#define HH 128
#define GG 64
#define EPS 1e-5f

// monotonic float <-> uint mapping for atomicMax on floats of any sign
__device__ __forceinline__ unsigned femax_enc(float f) {
    unsigned u = __float_as_uint(f);
    return (u & 0x80000000u) ? ~u : (u | 0x80000000u);
}
__device__ __forceinline__ float femax_dec(unsigned u) {
    return (u & 0x80000000u) ? __uint_as_float(u & 0x7FFFFFFFu) : __uint_as_float(~u);
}

// ---------------- CSR build ----------------
__global__ void k_count(const int* __restrict__ dst, int* __restrict__ cnt, int E) {
    int i = blockIdx.x * blockDim.x + threadIdx.x;
    if (i < E) atomicAdd(&cnt[dst[i]], 1);
}

__global__ __launch_bounds__(512) void k_scanA(const int* __restrict__ cnt, int* __restrict__ tmp,
                                               int* __restrict__ bsum, int n) {
    __shared__ int s[512];
    int t = threadIdx.x;
    int i = blockIdx.x * 512 + t;
    s[t] = (i < n) ? cnt[i] : 0;
    __syncthreads();
    for (int o = 1; o < 512; o <<= 1) {
        int u = (t >= o) ? s[t - o] : 0;
        __syncthreads();
        s[t] += u;
        __syncthreads();
    }
    if (i < n) tmp[i] = s[t];
    if (t == 511) bsum[blockIdx.x] = s[511];
}

__global__ __launch_bounds__(512) void k_scanB(int* __restrict__ bsum, int nb) {
    __shared__ int s[512];
    int t = threadIdx.x;
    s[t] = (t < nb) ? bsum[t] : 0;
    __syncthreads();
    for (int o = 1; o < 512; o <<= 1) {
        int u = (t >= o) ? s[t - o] : 0;
        __syncthreads();
        s[t] += u;
        __syncthreads();
    }
    if (t < nb) bsum[t] = s[t];
}

// rowptr + dinv fused
__global__ void k_scanC(const int* __restrict__ tmp, const int* __restrict__ bsum,
                        const int* __restrict__ cnt, int* __restrict__ rowptr,
                        float* __restrict__ dinv, int n) {
    int i = blockIdx.x * blockDim.x + threadIdx.x;
    if (i < n) {
        int b = i >> 9;
        int off = (b > 0) ? bsum[b - 1] : 0;
        rowptr[i + 1] = tmp[i] + off;
        if (i == 0) rowptr[0] = 0;
        dinv[i] = rsqrtf((float)(cnt[i] + 1));
    }
}

// fill packed (col, norm) pairs
__global__ void k_fill(const int* __restrict__ src, const int* __restrict__ dst,
                       const int* __restrict__ rowptr, int* __restrict__ cursor,
                       const float* __restrict__ dinv, int2* __restrict__ epk, int E) {
    int e = blockIdx.x * blockDim.x + threadIdx.x;
    if (e < E) {
        int s0 = src[e], d0 = dst[e];
        int p = atomicAdd(&cursor[d0], 1);
        int idx = rowptr[d0] + p;
        epk[idx] = make_int2(s0, __float_as_int(dinv[s0] * dinv[d0]));
    }
}

// ---------------- Persistent-block GEMM with fused BN-apply staging ----------------
// Grid = 256 blocks (1/CU, 132KB LDS). W resident in LDS (loaded once per block).
// Grid-stride over 64-row tiles; A double-buffered in LDS with register prefetch.
// Thread (tx=t&15, ty=t>>4) owns rows ty+16i (i<4), cols {4tx..4tx+3, 64+4tx..64+4tx+3}.
// W LDS reads: lanes stride 4 words -> 2-way bank alias (free). z stores: dense 256B segments.
// BNIN==1: stage h=relu(bn(Ain))(+res), h in-place to Aio.  ACT==1: fused tanh-GEMV + max.
#define FMA_ROW(i, a)                       \
    acc[i][0] = fmaf(a, w0.x, acc[i][0]);   \
    acc[i][1] = fmaf(a, w0.y, acc[i][1]);   \
    acc[i][2] = fmaf(a, w0.z, acc[i][2]);   \
    acc[i][3] = fmaf(a, w0.w, acc[i][3]);   \
    acc[i][4] = fmaf(a, w1.x, acc[i][4]);   \
    acc[i][5] = fmaf(a, w1.y, acc[i][5]);   \
    acc[i][6] = fmaf(a, w1.z, acc[i][6]);   \
    acc[i][7] = fmaf(a, w1.w, acc[i][7]);

#define QUAD(kk, a0e, a1e, a2e, a3e) {                  \
    float4 w0 = *(const float4*)&Wl[k + kk][ca];        \
    float4 w1 = *(const float4*)&Wl[k + kk][cb];        \
    FMA_ROW(0, a0e) FMA_ROW(1, a1e)                     \
    FMA_ROW(2, a2e) FMA_ROW(3, a3e) }

template <int BNIN, int ACT>
__global__ __launch_bounds__(256, 1) void k_gemm(const float* __restrict__ Ain, float* __restrict__ Aio,
                                                 const float* __restrict__ res,
                                                 const float* __restrict__ csum, const float* __restrict__ csq,
                                                 const float* __restrict__ bng, const float* __restrict__ bnb,
                                                 const float* __restrict__ W, const float* __restrict__ bias,
                                                 float* __restrict__ C, const float* __restrict__ w2,
                                                 const float* __restrict__ b2, unsigned* __restrict__ gmax,
                                                 int n) {
    __shared__ float Wl[128][132];      // 67.6 KB, resident all kernel
    __shared__ float Ab[2][64][132];    // 67.6 KB double-buffered A tile -> 135 KB total
    __shared__ float wm[4];
    int t = threadIdx.x;
    int tx = t & 15, ty = t >> 4;
    int ca = tx << 2;                   // cols ca..ca+3
    int cb = 64 + (tx << 2);            // cols cb..cb+3
    int c4 = (t & 31) << 2;             // staging column group
    int sr = t >> 5;                    // staging row base 0..7
    int ntiles = (n + 63) >> 6;

    // BN coefficients for this thread's staging columns
    float A0c = 0.f, A1c = 0.f, A2c = 0.f, A3c = 0.f;
    float B0c = 0.f, B1c = 0.f, B2c = 0.f, B3c = 0.f;
    if (BNIN) {
        float4 cs = *(const float4*)&csum[c4];
        float4 cq = *(const float4*)&csq[c4];
        float4 gg = *(const float4*)&bng[c4];
        float4 bb = *(const float4*)&bnb[c4];
        float inv_n = 1.0f / (float)n;
        float m0 = cs.x * inv_n, m1 = cs.y * inv_n, m2 = cs.z * inv_n, m3 = cs.w * inv_n;
        A0c = rsqrtf(cq.x * inv_n - m0 * m0 + EPS) * gg.x;
        A1c = rsqrtf(cq.y * inv_n - m1 * m1 + EPS) * gg.y;
        A2c = rsqrtf(cq.z * inv_n - m2 * m2 + EPS) * gg.z;
        A3c = rsqrtf(cq.w * inv_n - m3 * m3 + EPS) * gg.w;
        B0c = bb.x - m0 * A0c; B1c = bb.y - m1 * A1c; B2c = bb.z - m2 * A2c; B3c = bb.w - m3 * A3c;
    }

    // W preload (once per block): 256 threads = 32 colgroups x 8 row-lanes;
    // 16 iters at stride 8 -> rows {sr, sr+8, ..., sr+120} cover 0..127 exactly.
    // (R11 bug: 8 iters at stride 16 covered only half the rows.)
#pragma unroll
    for (int i = 0; i < 16; ++i) {
        int r = sr + (i << 3);
        *(float4*)&Wl[r][c4] = *(const float4*)&W[(size_t)r * HH + c4];
    }

    float4 aR[8], rR[8];
    int tile = blockIdx.x;
    // prologue loads
    if (tile < ntiles) {
        int tb = tile << 6;
        int rows = n - tb; if (rows > 64) rows = 64;
#pragma unroll
        for (int j = 0; j < 8; ++j) {
            int r = sr + (j << 3);
            if (r < rows) {
                size_t go = (size_t)(tb + r) * HH + c4;
                aR[j] = *(const float4*)&Ain[go];
                if (BNIN && res) rR[j] = *(const float4*)&res[go];
            }
        }
    }
    int cur = 0;
    for (; tile < ntiles; tile += gridDim.x) {
        int tb = tile << 6;
        int rows = n - tb; if (rows > 64) rows = 64;
        // commit: BN + residual + in-place h write + LDS write (consumes aR/rR)
#pragma unroll
        for (int j = 0; j < 8; ++j) {
            int r = sr + (j << 3);
            if (r < rows) {
                float4 v = aR[j];
                if (BNIN) {
                    v.x = fmaxf(fmaf(v.x, A0c, B0c), 0.f);
                    v.y = fmaxf(fmaf(v.y, A1c, B1c), 0.f);
                    v.z = fmaxf(fmaf(v.z, A2c, B2c), 0.f);
                    v.w = fmaxf(fmaf(v.w, A3c, B3c), 0.f);
                    if (res) {
                        float4 rv = rR[j];
                        v.x += rv.x; v.y += rv.y; v.z += rv.z; v.w += rv.w;
                    }
                    *(float4*)&Aio[(size_t)(tb + r) * HH + c4] = v;
                }
                *(float4*)&Ab[cur][r][c4] = v;
            }
        }
        // issue next tile's loads before the barrier (land during compute)
        int nxt = tile + gridDim.x;
        if (nxt < ntiles) {
            int tb2 = nxt << 6;
            int rows2 = n - tb2; if (rows2 > 64) rows2 = 64;
#pragma unroll
            for (int j = 0; j < 8; ++j) {
                int r = sr + (j << 3);
                if (r < rows2) {
                    size_t go = (size_t)(tb2 + r) * HH + c4;
                    aR[j] = *(const float4*)&Ain[go];
                    if (BNIN && res) rR[j] = *(const float4*)&res[go];
                }
            }
        }
        __syncthreads();   // Ab[cur] (and Wl on first iter) visible
        // compute 64x128 tile
        float acc[4][8] = {};
#pragma unroll 4
        for (int k = 0; k < 128; k += 4) {
            float4 a0 = *(const float4*)&Ab[cur][ty][k];
            float4 a1 = *(const float4*)&Ab[cur][ty + 16][k];
            float4 a2 = *(const float4*)&Ab[cur][ty + 32][k];
            float4 a3 = *(const float4*)&Ab[cur][ty + 48][k];
            QUAD(0, a0.x, a1.x, a2.x, a3.x)
            QUAD(1, a0.y, a1.y, a2.y, a3.y)
            QUAD(2, a0.z, a1.z, a2.z, a3.z)
            QUAD(3, a0.w, a1.w, a2.w, a3.w)
        }
        if (ACT == 0) {
#pragma unroll
            for (int i = 0; i < 4; ++i) {
                int r = tb + ty + (i << 4);
                if (r < n) {
                    float4 o0 = {acc[i][0], acc[i][1], acc[i][2], acc[i][3]};
                    float4 o1 = {acc[i][4], acc[i][5], acc[i][6], acc[i][7]};
                    *(float4*)&C[(size_t)r * HH + ca] = o0;
                    *(float4*)&C[(size_t)r * HH + cb] = o1;
                }
            }
        } else {
            // fused attention GEMV: apre[r] = sum_c tanh(acc+b1[c]) * w2[c] + b2; track max
            float b1v[8], w2v[8];
#pragma unroll
            for (int j = 0; j < 4; ++j) {
                b1v[j] = bias[ca + j];     w2v[j] = w2[ca + j];
                b1v[4 + j] = bias[cb + j]; w2v[4 + j] = w2[cb + j];
            }
            float b2s = b2[0];
            float lmax = -3.4e38f;
#pragma unroll
            for (int i = 0; i < 4; ++i) {
                float s = 0.f;
#pragma unroll
                for (int j = 0; j < 8; ++j)
                    s = fmaf(tanhf(acc[i][j] + b1v[j]), w2v[j], s);
                s += __shfl_xor(s, 1);
                s += __shfl_xor(s, 2);
                s += __shfl_xor(s, 4);
                s += __shfl_xor(s, 8);
                int r = tb + ty + (i << 4);
                float val = s + b2s;
                if (r < n) {
                    lmax = fmaxf(lmax, val);
                    if (tx == 0) C[r] = val;
                }
            }
            lmax = fmaxf(lmax, __shfl_xor(lmax, 16));
            lmax = fmaxf(lmax, __shfl_xor(lmax, 32));
            if ((t & 63) == 0) wm[t >> 6] = lmax;
            __syncthreads();
            if (t == 0) {
                float m = fmaxf(fmaxf(wm[0], wm[1]), fmaxf(wm[2], wm[3]));
                atomicMax(gmax, femax_enc(m));
            }
        }
        cur ^= 1;
    }
}

// ---------------- Aggregation ----------------
#define AGG_FMA(vv, ww)                                           \
    acc.x = fmaf(vv.x, ww, acc.x); acc.y = fmaf(vv.y, ww, acc.y); \
    acc.z = fmaf(vv.z, ww, acc.z); acc.w = fmaf(vv.w, ww, acc.w);

__global__ __launch_bounds__(256) void k_agg(const float* __restrict__ z, const int* __restrict__ rowptr,
                                             const int2* __restrict__ epk, const float* __restrict__ dinv,
                                             const float* __restrict__ bias, float* __restrict__ agg, int n) {
    int wid = (int)((blockIdx.x * (size_t)blockDim.x + threadIdx.x) >> 6);
    if (wid >= n) return;
    int lane = threadIdx.x & 63;
    int half = lane >> 5;
    int c0 = (lane & 31) << 2;
    int beg = rowptr[wid], end = rowptr[wid + 1];
    float4 acc = {0.f, 0.f, 0.f, 0.f};
    if (half == 0) {
        float di = dinv[wid];
        float ws = di * di;
        float4 zs = *(const float4*)&z[(size_t)wid * HH + c0];
        acc.x = zs.x * ws; acc.y = zs.y * ws; acc.z = zs.z * ws; acc.w = zs.w * ws;
    }
    for (int e = beg + half; e < end; e += 16) {
        int2 p[8];
        float w[8];
#pragma unroll
        for (int j = 0; j < 8; ++j) {
            int idx = e + 2 * j;
            bool valid = idx < end;
            p[j] = epk[valid ? idx : beg];
            w[j] = valid ? __int_as_float(p[j].y) : 0.f;
        }
        float4 v[8];
#pragma unroll
        for (int j = 0; j < 8; ++j)
            v[j] = *(const float4*)&z[(size_t)p[j].x * HH + c0];
#pragma unroll
        for (int j = 0; j < 8; ++j) { AGG_FMA(v[j], w[j]) }
    }
    acc.x += __shfl_xor(acc.x, 32);
    acc.y += __shfl_xor(acc.y, 32);
    acc.z += __shfl_xor(acc.z, 32);
    acc.w += __shfl_xor(acc.w, 32);
    if (half == 0) {
        float4 b4 = *(const float4*)&bias[c0];
        acc.x += b4.x; acc.y += b4.y; acc.z += b4.z; acc.w += b4.w;
        *(float4*)&agg[(size_t)wid * HH + c0] = acc;
    }
}

// ---------------- BatchNorm stats ----------------
__global__ __launch_bounds__(256) void k_bnstats(const float* __restrict__ agg, float* __restrict__ colsum,
                                                 float* __restrict__ colsq, int n) {
    int t = threadIdx.x;
    int col = t & 127, sub = t >> 7;
    int rpb = (n + gridDim.x - 1) / gridDim.x;
    int r0 = blockIdx.x * rpb;
    int r1 = r0 + rpb; if (r1 > n) r1 = n;
    float s = 0.f, q = 0.f;
    for (int r = r0 + sub; r < r1; r += 2) {
        float v = agg[(size_t)r * HH + col];
        s += v;
        q = fmaf(v, v, q);
    }
    __shared__ float ls[256], lq[256];
    ls[t] = s; lq[t] = q;
    __syncthreads();
    if (t < 128) {
        atomicAdd(&colsum[col], ls[t] + ls[t + 128]);
        atomicAdd(&colsq[col], lq[t] + lq[t + 128]);
    }
}

// ---------------- Pooling (batch sorted) + global exp-sum ----------------
__global__ __launch_bounds__(256) void k_pool(const float* __restrict__ h, const float* __restrict__ apre,
                                              const int* __restrict__ batch, const unsigned* __restrict__ gmax,
                                              float* __restrict__ pooled, float* __restrict__ counts,
                                              float* __restrict__ Sglob, int n) {
    float M = femax_dec(*gmax);
    int t = threadIdx.x;
    int col = t & 127, sub = t >> 7;
    int rpb = (n + gridDim.x - 1) / gridDim.x;
    int r0 = blockIdx.x * rpb;
    int r1 = r0 + rpb; if (r1 > n) r1 = n;
    float acc = 0.f, cntf = 0.f, es = 0.f;
    int cur = -1;
    for (int r = r0 + sub; r < r1; r += 2) {
        int g = batch[r];
        if (g != cur) {
            if (cur >= 0) {
                atomicAdd(&pooled[cur * HH + col], acc);
                if (col == 0) atomicAdd(&counts[cur], cntf);
            }
            cur = g; acc = 0.f; cntf = 0.f;
        }
        float s = expf(apre[r] - M);
        acc = fmaf(h[(size_t)r * HH + col], s, acc);
        cntf += 1.0f;
        if (col == 0) es += s;
    }
    if (cur >= 0) {
        atomicAdd(&pooled[cur * HH + col], acc);
        if (col == 0) atomicAdd(&counts[cur], cntf);
    }
    if (col == 0 && es != 0.f) atomicAdd(Sglob, es);
}

// ---------------- Final MLP ----------------
__global__ __launch_bounds__(128) void k_mlp(const float* __restrict__ pooled, const float* __restrict__ counts,
                                             const float* __restrict__ Sglob, const float* __restrict__ W1,
                                             const float* __restrict__ b1, const float* __restrict__ W2,
                                             const float* __restrict__ b2, float* __restrict__ out) {
    int g = blockIdx.x;
    int t = threadIdx.x;
    __shared__ float p[128], t1[128];
    float S = Sglob[0];
    float c = fmaxf(counts[g], 1.0f);
    p[t] = pooled[g * HH + t] / (S * c);
    __syncthreads();
    float acc = b1[t];
    for (int k = 0; k < 128; ++k) acc = fmaf(p[k], W1[k * HH + t], acc);
    t1[t] = fmaxf(acc, 0.f);
    __syncthreads();
    float acc2 = b2[t];
    for (int j = 0; j < 128; ++j) acc2 = fmaf(t1[j], W2[j * HH + t], acc2);
    out[g * HH + t] = acc2;
}

extern "C" void kernel_launch(void* const* d_in, const int* in_sizes, int n_in,
                              void* d_out, int out_size, void* d_ws, size_t ws_size,
                              hipStream_t stream) {
    const float* x       = (const float*)d_in[0];
    const int*   ei      = (const int*)d_in[1];
    const int*   batch   = (const int*)d_in[2];
    const float* conv_w  = (const float*)d_in[3];
    const float* conv_b  = (const float*)d_in[4];
    const float* bn_g    = (const float*)d_in[5];
    const float* bn_b    = (const float*)d_in[6];
    const float* attn_w1 = (const float*)d_in[7];
    const float* attn_b1 = (const float*)d_in[8];
    const float* attn_w2 = (const float*)d_in[9];
    const float* attn_b2 = (const float*)d_in[10];
    const float* proj_w1 = (const float*)d_in[11];
    const float* proj_b1 = (const float*)d_in[12];
    const float* proj_w2 = (const float*)d_in[13];
    const float* proj_b2 = (const float*)d_in[14];

    const int E = in_sizes[1] / 2;
    const int n = in_sizes[2];
    const int* srcp = ei;
    const int* dstp = ei + E;

    // ---- workspace layout ----
    char* base = (char*)d_ws;
    size_t off = 0;
    auto alloc = [&](size_t bytes) -> char* {
        char* p = base + off;
        off = (off + bytes + 511) & ~(size_t)511;
        return p;
    };
    int*   cntcur  = (int*)alloc((size_t)2 * n * 4);     // cnt | cursor (one memset)
    int*   cnt     = cntcur;
    int*   cursor  = cntcur + n;
    int*   rowptr  = (int*)alloc((size_t)(n + 1) * 4);
    int*   tmp     = (int*)alloc((size_t)n * 4);
    int*   bsum    = (int*)alloc(512 * 4);
    float* dinv    = (float*)alloc((size_t)n * 4);
    int2*  epk     = (int2*)alloc((size_t)E * 8);
    float* z       = (float*)alloc((size_t)n * HH * 4);
    float* aggA    = (float*)alloc((size_t)n * HH * 4);
    float* aggB    = (float*)alloc((size_t)n * HH * 4);
    float* apre    = (float*)alloc((size_t)n * 4);
    // zero arena: colstats(3*256 floats) | gmax(1) | S(1) | pad->1024 | pooled(8192) | counts(64)
    float* zarena  = (float*)alloc((size_t)(1024 + GG * HH + GG) * 4);
    float* cs0 = zarena;            float* cq0 = zarena + 128;
    float* cs1 = zarena + 256;      float* cq1 = zarena + 384;
    float* cs2 = zarena + 512;      float* cq2 = zarena + 640;
    unsigned* gmaxu = (unsigned*)(zarena + 768);
    float* Sglob  = zarena + 769;
    float* pooled = zarena + 1024;
    float* counts = zarena + 1024 + GG * HH;
    const size_t zbytes = (size_t)(1024 + GG * HH + GG) * 4;

    const int eGrid    = (E + 255) / 256;
    const int nGrid    = (n + 255) / 256;
    const int nbScan   = (n + 511) / 512;
    const int waveGrid = (n + 3) / 4;

    // ---- zero accumulators + CSR build ----
    hipMemsetAsync(zarena, 0, zbytes, stream);
    hipMemsetAsync(cntcur, 0, (size_t)2 * n * 4, stream);
    k_count<<<eGrid, 256, 0, stream>>>(dstp, cnt, E);
    k_scanA<<<nbScan, 512, 0, stream>>>(cnt, tmp, bsum, n);
    k_scanB<<<1, 512, 0, stream>>>(bsum, nbScan);
    k_scanC<<<nGrid, 256, 0, stream>>>(tmp, bsum, cnt, rowptr, dinv, n);
    k_fill<<<eGrid, 256, 0, stream>>>(srcp, dstp, rowptr, cursor, dinv, epk, E);

    // ---- layer 0 ----
    k_gemm<0, 0><<<256, 256, 0, stream>>>(x, nullptr, nullptr, nullptr, nullptr, nullptr, nullptr,
                                          conv_w, nullptr, z, nullptr, nullptr, nullptr, n);
    k_agg<<<waveGrid, 256, 0, stream>>>(z, rowptr, epk, dinv, conv_b, aggA, n);
    k_bnstats<<<1024, 256, 0, stream>>>(aggA, cs0, cq0, n);

    // ---- layer 1 (BN0 fused into staging; h1 -> aggA in place) ----
    k_gemm<1, 0><<<256, 256, 0, stream>>>(aggA, aggA, nullptr, cs0, cq0, bn_g, bn_b,
                                          conv_w + (size_t)HH * HH, nullptr, z, nullptr, nullptr,
                                          nullptr, n);
    k_agg<<<waveGrid, 256, 0, stream>>>(z, rowptr, epk, dinv, conv_b + HH, aggB, n);
    k_bnstats<<<1024, 256, 0, stream>>>(aggB, cs1, cq1, n);

    // ---- layer 2 (BN1 fused; res=h1(aggA); h2 -> aggB in place) ----
    k_gemm<1, 0><<<256, 256, 0, stream>>>(aggB, aggB, aggA, cs1, cq1, bn_g + HH, bn_b + HH,
                                          conv_w + (size_t)2 * HH * HH, nullptr, z, nullptr, nullptr,
                                          nullptr, n);
    k_agg<<<waveGrid, 256, 0, stream>>>(z, rowptr, epk, dinv, conv_b + 2 * HH, aggA, n);
    k_bnstats<<<1024, 256, 0, stream>>>(aggA, cs2, cq2, n);

    // ---- attention gemm (BN2 fused; res=h2(aggB); h3 -> aggA in place; GEMV+max epilogue) ----
    k_gemm<1, 1><<<256, 256, 0, stream>>>(aggA, aggA, aggB, cs2, cq2, bn_g + 2 * HH, bn_b + 2 * HH,
                                          attn_w1, attn_b1, apre, attn_w2, attn_b2, gmaxu, n);

    // ---- pooling (+ global exp-sum) + MLP ----
    k_pool<<<1024, 256, 0, stream>>>(aggA, apre, batch, gmaxu, pooled, counts, Sglob, n);
    k_mlp<<<GG, 128, 0, stream>>>(pooled, counts, Sglob, proj_w1, proj_b1, proj_w2, proj_b2,
                                  (float*)d_out);
}

// Round 13
// 1003.995 us; speedup vs baseline: 1.4544x; 1.1196x over previous
//
#include <hip/hip_runtime.h>

#define HH 128
#define GG 64
#define EPS 1e-5f

// monotonic float <-> uint mapping for atomicMax on floats of any sign
__device__ __forceinline__ unsigned femax_enc(float f) {
    unsigned u = __float_as_uint(f);
    return (u & 0x80000000u) ? ~u : (u | 0x80000000u);
}
__device__ __forceinline__ float femax_dec(unsigned u) {
    return (u & 0x80000000u) ? __uint_as_float(u & 0x7FFFFFFFu) : __uint_as_float(~u);
}
// fp32 -> bf16 bits (RNE)
__device__ __forceinline__ unsigned f2bf(float f) {
    unsigned u = __float_as_uint(f);
    return (u + 0x7FFFu + ((u >> 16) & 1u)) >> 16;
}
// unpack uint2 (4 bf16) -> float4
#define UNPK(q, vv) {                                      \
    vv.x = __uint_as_float((q.x & 0xFFFFu) << 16);         \
    vv.y = __uint_as_float(q.x & 0xFFFF0000u);             \
    vv.z = __uint_as_float((q.y & 0xFFFFu) << 16);         \
    vv.w = __uint_as_float(q.y & 0xFFFF0000u); }

// ---------------- CSR build ----------------
__global__ void k_count(const int* __restrict__ dst, int* __restrict__ cnt, int E) {
    int i = blockIdx.x * blockDim.x + threadIdx.x;
    if (i < E) atomicAdd(&cnt[dst[i]], 1);
}

__global__ __launch_bounds__(512) void k_scanA(const int* __restrict__ cnt, int* __restrict__ tmp,
                                               int* __restrict__ bsum, int n) {
    __shared__ int s[512];
    int t = threadIdx.x;
    int i = blockIdx.x * 512 + t;
    s[t] = (i < n) ? cnt[i] : 0;
    __syncthreads();
    for (int o = 1; o < 512; o <<= 1) {
        int u = (t >= o) ? s[t - o] : 0;
        __syncthreads();
        s[t] += u;
        __syncthreads();
    }
    if (i < n) tmp[i] = s[t];
    if (t == 511) bsum[blockIdx.x] = s[511];
}

__global__ __launch_bounds__(512) void k_scanB(int* __restrict__ bsum, int nb) {
    __shared__ int s[512];
    int t = threadIdx.x;
    s[t] = (t < nb) ? bsum[t] : 0;
    __syncthreads();
    for (int o = 1; o < 512; o <<= 1) {
        int u = (t >= o) ? s[t - o] : 0;
        __syncthreads();
        s[t] += u;
        __syncthreads();
    }
    if (t < nb) bsum[t] = s[t];
}

// rowptr + dinv fused
__global__ void k_scanC(const int* __restrict__ tmp, const int* __restrict__ bsum,
                        const int* __restrict__ cnt, int* __restrict__ rowptr,
                        float* __restrict__ dinv, int n) {
    int i = blockIdx.x * blockDim.x + threadIdx.x;
    if (i < n) {
        int b = i >> 9;
        int off = (b > 0) ? bsum[b - 1] : 0;
        rowptr[i + 1] = tmp[i] + off;
        if (i == 0) rowptr[0] = 0;
        dinv[i] = rsqrtf((float)(cnt[i] + 1));
    }
}

// fill packed (col, norm) pairs
__global__ void k_fill(const int* __restrict__ src, const int* __restrict__ dst,
                       const int* __restrict__ rowptr, int* __restrict__ cursor,
                       const float* __restrict__ dinv, int2* __restrict__ epk, int E) {
    int e = blockIdx.x * blockDim.x + threadIdx.x;
    if (e < E) {
        int s0 = src[e], d0 = dst[e];
        int p = atomicAdd(&cursor[d0], 1);
        int idx = rowptr[d0] + p;
        epk[idx] = make_int2(s0, __float_as_int(dinv[s0] * dinv[d0]));
    }
}

// ---------------- Persistent-block GEMM with fused BN-apply staging ----------------
// Grid = 256 blocks (1/CU, 135KB LDS). W resident in LDS (loaded once per block).
// Grid-stride over 64-row tiles; A double-buffered in LDS with register prefetch.
// ACT==0: z output in BF16 (halves agg's gather bytes + z write traffic).
#define FMA_ROW(i, a)                       \
    acc[i][0] = fmaf(a, w0.x, acc[i][0]);   \
    acc[i][1] = fmaf(a, w0.y, acc[i][1]);   \
    acc[i][2] = fmaf(a, w0.z, acc[i][2]);   \
    acc[i][3] = fmaf(a, w0.w, acc[i][3]);   \
    acc[i][4] = fmaf(a, w1.x, acc[i][4]);   \
    acc[i][5] = fmaf(a, w1.y, acc[i][5]);   \
    acc[i][6] = fmaf(a, w1.z, acc[i][6]);   \
    acc[i][7] = fmaf(a, w1.w, acc[i][7]);

#define QUAD(kk, a0e, a1e, a2e, a3e) {                  \
    float4 w0 = *(const float4*)&Wl[k + kk][ca];        \
    float4 w1 = *(const float4*)&Wl[k + kk][cb];        \
    FMA_ROW(0, a0e) FMA_ROW(1, a1e)                     \
    FMA_ROW(2, a2e) FMA_ROW(3, a3e) }

template <int BNIN, int ACT>
__global__ __launch_bounds__(256, 1) void k_gemm(const float* __restrict__ Ain, float* __restrict__ Aio,
                                                 const float* __restrict__ res,
                                                 const float* __restrict__ csum, const float* __restrict__ csq,
                                                 const float* __restrict__ bng, const float* __restrict__ bnb,
                                                 const float* __restrict__ W, const float* __restrict__ bias,
                                                 float* __restrict__ C, const float* __restrict__ w2,
                                                 const float* __restrict__ b2, unsigned* __restrict__ gmax,
                                                 int n) {
    __shared__ float Wl[128][132];      // 67.6 KB, resident all kernel
    __shared__ float Ab[2][64][132];    // 67.6 KB double-buffered A tile
    __shared__ float wm[4];
    int t = threadIdx.x;
    int tx = t & 15, ty = t >> 4;
    int ca = tx << 2;                   // cols ca..ca+3
    int cb = 64 + (tx << 2);            // cols cb..cb+3
    int c4 = (t & 31) << 2;             // staging column group
    int sr = t >> 5;                    // staging row base 0..7
    int ntiles = (n + 63) >> 6;

    // BN coefficients for this thread's staging columns
    float A0c = 0.f, A1c = 0.f, A2c = 0.f, A3c = 0.f;
    float B0c = 0.f, B1c = 0.f, B2c = 0.f, B3c = 0.f;
    if (BNIN) {
        float4 cs = *(const float4*)&csum[c4];
        float4 cq = *(const float4*)&csq[c4];
        float4 gg = *(const float4*)&bng[c4];
        float4 bb = *(const float4*)&bnb[c4];
        float inv_n = 1.0f / (float)n;
        float m0 = cs.x * inv_n, m1 = cs.y * inv_n, m2 = cs.z * inv_n, m3 = cs.w * inv_n;
        A0c = rsqrtf(cq.x * inv_n - m0 * m0 + EPS) * gg.x;
        A1c = rsqrtf(cq.y * inv_n - m1 * m1 + EPS) * gg.y;
        A2c = rsqrtf(cq.z * inv_n - m2 * m2 + EPS) * gg.z;
        A3c = rsqrtf(cq.w * inv_n - m3 * m3 + EPS) * gg.w;
        B0c = bb.x - m0 * A0c; B1c = bb.y - m1 * A1c; B2c = bb.z - m2 * A2c; B3c = bb.w - m3 * A3c;
    }

    // W preload (once per block): 16 iters at stride 8 -> rows 0..127 exactly
#pragma unroll
    for (int i = 0; i < 16; ++i) {
        int r = sr + (i << 3);
        *(float4*)&Wl[r][c4] = *(const float4*)&W[(size_t)r * HH + c4];
    }

    float4 aR[8], rR[8];
    int tile = blockIdx.x;
    if (tile < ntiles) {
        int tb = tile << 6;
        int rows = n - tb; if (rows > 64) rows = 64;
#pragma unroll
        for (int j = 0; j < 8; ++j) {
            int r = sr + (j << 3);
            if (r < rows) {
                size_t go = (size_t)(tb + r) * HH + c4;
                aR[j] = *(const float4*)&Ain[go];
                if (BNIN && res) rR[j] = *(const float4*)&res[go];
            }
        }
    }
    int cur = 0;
    for (; tile < ntiles; tile += gridDim.x) {
        int tb = tile << 6;
        int rows = n - tb; if (rows > 64) rows = 64;
        // commit: BN + residual + in-place h write + LDS write
#pragma unroll
        for (int j = 0; j < 8; ++j) {
            int r = sr + (j << 3);
            if (r < rows) {
                float4 v = aR[j];
                if (BNIN) {
                    v.x = fmaxf(fmaf(v.x, A0c, B0c), 0.f);
                    v.y = fmaxf(fmaf(v.y, A1c, B1c), 0.f);
                    v.z = fmaxf(fmaf(v.z, A2c, B2c), 0.f);
                    v.w = fmaxf(fmaf(v.w, A3c, B3c), 0.f);
                    if (res) {
                        float4 rv = rR[j];
                        v.x += rv.x; v.y += rv.y; v.z += rv.z; v.w += rv.w;
                    }
                    *(float4*)&Aio[(size_t)(tb + r) * HH + c4] = v;
                }
                *(float4*)&Ab[cur][r][c4] = v;
            }
        }
        // issue next tile's loads before the barrier (land during compute)
        int nxt = tile + gridDim.x;
        if (nxt < ntiles) {
            int tb2 = nxt << 6;
            int rows2 = n - tb2; if (rows2 > 64) rows2 = 64;
#pragma unroll
            for (int j = 0; j < 8; ++j) {
                int r = sr + (j << 3);
                if (r < rows2) {
                    size_t go = (size_t)(tb2 + r) * HH + c4;
                    aR[j] = *(const float4*)&Ain[go];
                    if (BNIN && res) rR[j] = *(const float4*)&res[go];
                }
            }
        }
        __syncthreads();   // Ab[cur] (and Wl on first iter) visible
        float acc[4][8] = {};
#pragma unroll 4
        for (int k = 0; k < 128; k += 4) {
            float4 a0 = *(const float4*)&Ab[cur][ty][k];
            float4 a1 = *(const float4*)&Ab[cur][ty + 16][k];
            float4 a2 = *(const float4*)&Ab[cur][ty + 32][k];
            float4 a3 = *(const float4*)&Ab[cur][ty + 48][k];
            QUAD(0, a0.x, a1.x, a2.x, a3.x)
            QUAD(1, a0.y, a1.y, a2.y, a3.y)
            QUAD(2, a0.z, a1.z, a2.z, a3.z)
            QUAD(3, a0.w, a1.w, a2.w, a3.w)
        }
        if (ACT == 0) {
            // bf16 z output: two 8B stores per row (cols ca..ca+3, cb..cb+3)
            unsigned short* Cb = (unsigned short*)C;
#pragma unroll
            for (int i = 0; i < 4; ++i) {
                int r = tb + ty + (i << 4);
                if (r < n) {
                    uint2 o0, o1;
                    o0.x = f2bf(acc[i][0]) | (f2bf(acc[i][1]) << 16);
                    o0.y = f2bf(acc[i][2]) | (f2bf(acc[i][3]) << 16);
                    o1.x = f2bf(acc[i][4]) | (f2bf(acc[i][5]) << 16);
                    o1.y = f2bf(acc[i][6]) | (f2bf(acc[i][7]) << 16);
                    *(uint2*)&Cb[(size_t)r * HH + ca] = o0;
                    *(uint2*)&Cb[(size_t)r * HH + cb] = o1;
                }
            }
        } else {
            // fused attention GEMV: apre[r] = sum_c tanh(acc+b1[c]) * w2[c] + b2; track max
            float b1v[8], w2v[8];
#pragma unroll
            for (int j = 0; j < 4; ++j) {
                b1v[j] = bias[ca + j];     w2v[j] = w2[ca + j];
                b1v[4 + j] = bias[cb + j]; w2v[4 + j] = w2[cb + j];
            }
            float b2s = b2[0];
            float lmax = -3.4e38f;
#pragma unroll
            for (int i = 0; i < 4; ++i) {
                float s = 0.f;
#pragma unroll
                for (int j = 0; j < 8; ++j)
                    s = fmaf(tanhf(acc[i][j] + b1v[j]), w2v[j], s);
                s += __shfl_xor(s, 1);
                s += __shfl_xor(s, 2);
                s += __shfl_xor(s, 4);
                s += __shfl_xor(s, 8);
                int r = tb + ty + (i << 4);
                float val = s + b2s;
                if (r < n) {
                    lmax = fmaxf(lmax, val);
                    if (tx == 0) C[r] = val;
                }
            }
            lmax = fmaxf(lmax, __shfl_xor(lmax, 16));
            lmax = fmaxf(lmax, __shfl_xor(lmax, 32));
            if ((t & 63) == 0) wm[t >> 6] = lmax;
            __syncthreads();
            if (t == 0) {
                float m = fmaxf(fmaxf(wm[0], wm[1]), fmaxf(wm[2], wm[3]));
                atomicMax(gmax, femax_enc(m));
            }
        }
        cur ^= 1;
    }
}

// ---------------- Aggregation (z in bf16: 256B gathers) ----------------
#define AGG_FMA(vv, ww)                                           \
    acc.x = fmaf(vv.x, ww, acc.x); acc.y = fmaf(vv.y, ww, acc.y); \
    acc.z = fmaf(vv.z, ww, acc.z); acc.w = fmaf(vv.w, ww, acc.w);

__global__ __launch_bounds__(256) void k_agg(const unsigned short* __restrict__ zb,
                                             const int* __restrict__ rowptr,
                                             const int2* __restrict__ epk, const float* __restrict__ dinv,
                                             const float* __restrict__ bias, float* __restrict__ agg, int n) {
    int wid = (int)((blockIdx.x * (size_t)blockDim.x + threadIdx.x) >> 6);
    if (wid >= n) return;
    int lane = threadIdx.x & 63;
    int half = lane >> 5;
    int c0 = (lane & 31) << 2;
    int beg = rowptr[wid], end = rowptr[wid + 1];
    float4 acc = {0.f, 0.f, 0.f, 0.f};
    if (half == 0) {
        float di = dinv[wid];
        float ws = di * di;
        uint2 qs = *(const uint2*)&zb[(size_t)wid * HH + c0];
        float4 zs; UNPK(qs, zs)
        acc.x = zs.x * ws; acc.y = zs.y * ws; acc.z = zs.z * ws; acc.w = zs.w * ws;
    }
    for (int e = beg + half; e < end; e += 16) {
        int2 p[8];
        float w[8];
#pragma unroll
        for (int j = 0; j < 8; ++j) {
            int idx = e + 2 * j;
            bool valid = idx < end;
            p[j] = epk[valid ? idx : beg];
            w[j] = valid ? __int_as_float(p[j].y) : 0.f;
        }
        uint2 q[8];
#pragma unroll
        for (int j = 0; j < 8; ++j)
            q[j] = *(const uint2*)&zb[(size_t)p[j].x * HH + c0];
#pragma unroll
        for (int j = 0; j < 8; ++j) {
            float4 v; UNPK(q[j], v)
            AGG_FMA(v, w[j])
        }
    }
    acc.x += __shfl_xor(acc.x, 32);
    acc.y += __shfl_xor(acc.y, 32);
    acc.z += __shfl_xor(acc.z, 32);
    acc.w += __shfl_xor(acc.w, 32);
    if (half == 0) {
        float4 b4 = *(const float4*)&bias[c0];
        acc.x += b4.x; acc.y += b4.y; acc.z += b4.z; acc.w += b4.w;
        *(float4*)&agg[(size_t)wid * HH + c0] = acc;
    }
}

// ---------------- BatchNorm stats ----------------
__global__ __launch_bounds__(256) void k_bnstats(const float* __restrict__ agg, float* __restrict__ colsum,
                                                 float* __restrict__ colsq, int n) {
    int t = threadIdx.x;
    int col = t & 127, sub = t >> 7;
    int rpb = (n + gridDim.x - 1) / gridDim.x;
    int r0 = blockIdx.x * rpb;
    int r1 = r0 + rpb; if (r1 > n) r1 = n;
    float s = 0.f, q = 0.f;
    for (int r = r0 + sub; r < r1; r += 2) {
        float v = agg[(size_t)r * HH + col];
        s += v;
        q = fmaf(v, v, q);
    }
    __shared__ float ls[256], lq[256];
    ls[t] = s; lq[t] = q;
    __syncthreads();
    if (t < 128) {
        atomicAdd(&colsum[col], ls[t] + ls[t + 128]);
        atomicAdd(&colsq[col], lq[t] + lq[t + 128]);
    }
}

// ---------------- Pooling (batch sorted) + global exp-sum ----------------
__global__ __launch_bounds__(256) void k_pool(const float* __restrict__ h, const float* __restrict__ apre,
                                              const int* __restrict__ batch, const unsigned* __restrict__ gmax,
                                              float* __restrict__ pooled, float* __restrict__ counts,
                                              float* __restrict__ Sglob, int n) {
    float M = femax_dec(*gmax);
    int t = threadIdx.x;
    int col = t & 127, sub = t >> 7;
    int rpb = (n + gridDim.x - 1) / gridDim.x;
    int r0 = blockIdx.x * rpb;
    int r1 = r0 + rpb; if (r1 > n) r1 = n;
    float acc = 0.f, cntf = 0.f, es = 0.f;
    int cur = -1;
    for (int r = r0 + sub; r < r1; r += 2) {
        int g = batch[r];
        if (g != cur) {
            if (cur >= 0) {
                atomicAdd(&pooled[cur * HH + col], acc);
                if (col == 0) atomicAdd(&counts[cur], cntf);
            }
            cur = g; acc = 0.f; cntf = 0.f;
        }
        float s = expf(apre[r] - M);
        acc = fmaf(h[(size_t)r * HH + col], s, acc);
        cntf += 1.0f;
        if (col == 0) es += s;
    }
    if (cur >= 0) {
        atomicAdd(&pooled[cur * HH + col], acc);
        if (col == 0) atomicAdd(&counts[cur], cntf);
    }
    if (col == 0 && es != 0.f) atomicAdd(Sglob, es);
}

// ---------------- Final MLP ----------------
__global__ __launch_bounds__(128) void k_mlp(const float* __restrict__ pooled, const float* __restrict__ counts,
                                             const float* __restrict__ Sglob, const float* __restrict__ W1,
                                             const float* __restrict__ b1, const float* __restrict__ W2,
                                             const float* __restrict__ b2, float* __restrict__ out) {
    int g = blockIdx.x;
    int t = threadIdx.x;
    __shared__ float p[128], t1[128];
    float S = Sglob[0];
    float c = fmaxf(counts[g], 1.0f);
    p[t] = pooled[g * HH + t] / (S * c);
    __syncthreads();
    float acc = b1[t];
    for (int k = 0; k < 128; ++k) acc = fmaf(p[k], W1[k * HH + t], acc);
    t1[t] = fmaxf(acc, 0.f);
    __syncthreads();
    float acc2 = b2[t];
    for (int j = 0; j < 128; ++j) acc2 = fmaf(t1[j], W2[j * HH + t], acc2);
    out[g * HH + t] = acc2;
}

extern "C" void kernel_launch(void* const* d_in, const int* in_sizes, int n_in,
                              void* d_out, int out_size, void* d_ws, size_t ws_size,
                              hipStream_t stream) {
    const float* x       = (const float*)d_in[0];
    const int*   ei      = (const int*)d_in[1];
    const int*   batch   = (const int*)d_in[2];
    const float* conv_w  = (const float*)d_in[3];
    const float* conv_b  = (const float*)d_in[4];
    const float* bn_g    = (const float*)d_in[5];
    const float* bn_b    = (const float*)d_in[6];
    const float* attn_w1 = (const float*)d_in[7];
    const float* attn_b1 = (const float*)d_in[8];
    const float* attn_w2 = (const float*)d_in[9];
    const float* attn_b2 = (const float*)d_in[10];
    const float* proj_w1 = (const float*)d_in[11];
    const float* proj_b1 = (const float*)d_in[12];
    const float* proj_w2 = (const float*)d_in[13];
    const float* proj_b2 = (const float*)d_in[14];

    const int E = in_sizes[1] / 2;
    const int n = in_sizes[2];
    const int* srcp = ei;
    const int* dstp = ei + E;

    // ---- workspace layout ----
    char* base = (char*)d_ws;
    size_t off = 0;
    auto alloc = [&](size_t bytes) -> char* {
        char* p = base + off;
        off = (off + bytes + 511) & ~(size_t)511;
        return p;
    };
    int*   cntcur  = (int*)alloc((size_t)2 * n * 4);     // cnt | cursor (one memset)
    int*   cnt     = cntcur;
    int*   cursor  = cntcur + n;
    int*   rowptr  = (int*)alloc((size_t)(n + 1) * 4);
    int*   tmp     = (int*)alloc((size_t)n * 4);
    int*   bsum    = (int*)alloc(512 * 4);
    float* dinv    = (float*)alloc((size_t)n * 4);
    int2*  epk     = (int2*)alloc((size_t)E * 8);
    unsigned short* zb = (unsigned short*)alloc((size_t)n * HH * 2);   // bf16 z
    float* aggA    = (float*)alloc((size_t)n * HH * 4);
    float* aggB    = (float*)alloc((size_t)n * HH * 4);
    float* apre    = (float*)alloc((size_t)n * 4);
    // zero arena: colstats(3*256 floats) | gmax(1) | S(1) | pad->1024 | pooled(8192) | counts(64)
    float* zarena  = (float*)alloc((size_t)(1024 + GG * HH + GG) * 4);
    float* cs0 = zarena;            float* cq0 = zarena + 128;
    float* cs1 = zarena + 256;      float* cq1 = zarena + 384;
    float* cs2 = zarena + 512;      float* cq2 = zarena + 640;
    unsigned* gmaxu = (unsigned*)(zarena + 768);
    float* Sglob  = zarena + 769;
    float* pooled = zarena + 1024;
    float* counts = zarena + 1024 + GG * HH;
    const size_t zbytes = (size_t)(1024 + GG * HH + GG) * 4;

    const int eGrid    = (E + 255) / 256;
    const int nGrid    = (n + 255) / 256;
    const int nbScan   = (n + 511) / 512;
    const int waveGrid = (n + 3) / 4;

    // ---- zero accumulators + CSR build ----
    hipMemsetAsync(zarena, 0, zbytes, stream);
    hipMemsetAsync(cntcur, 0, (size_t)2 * n * 4, stream);
    k_count<<<eGrid, 256, 0, stream>>>(dstp, cnt, E);
    k_scanA<<<nbScan, 512, 0, stream>>>(cnt, tmp, bsum, n);
    k_scanB<<<1, 512, 0, stream>>>(bsum, nbScan);
    k_scanC<<<nGrid, 256, 0, stream>>>(tmp, bsum, cnt, rowptr, dinv, n);
    k_fill<<<eGrid, 256, 0, stream>>>(srcp, dstp, rowptr, cursor, dinv, epk, E);

    // ---- layer 0 ----
    k_gemm<0, 0><<<256, 256, 0, stream>>>(x, nullptr, nullptr, nullptr, nullptr, nullptr, nullptr,
                                          conv_w, nullptr, (float*)zb, nullptr, nullptr, nullptr, n);
    k_agg<<<waveGrid, 256, 0, stream>>>(zb, rowptr, epk, dinv, conv_b, aggA, n);
    k_bnstats<<<1024, 256, 0, stream>>>(aggA, cs0, cq0, n);

    // ---- layer 1 (BN0 fused into staging; h1 -> aggA in place) ----
    k_gemm<1, 0><<<256, 256, 0, stream>>>(aggA, aggA, nullptr, cs0, cq0, bn_g, bn_b,
                                          conv_w + (size_t)HH * HH, nullptr, (float*)zb, nullptr, nullptr,
                                          nullptr, n);
    k_agg<<<waveGrid, 256, 0, stream>>>(zb, rowptr, epk, dinv, conv_b + HH, aggB, n);
    k_bnstats<<<1024, 256, 0, stream>>>(aggB, cs1, cq1, n);

    // ---- layer 2 (BN1 fused; res=h1(aggA); h2 -> aggB in place) ----
    k_gemm<1, 0><<<256, 256, 0, stream>>>(aggB, aggB, aggA, cs1, cq1, bn_g + HH, bn_b + HH,
                                          conv_w + (size_t)2 * HH * HH, nullptr, (float*)zb, nullptr, nullptr,
                                          nullptr, n);
    k_agg<<<waveGrid, 256, 0, stream>>>(zb, rowptr, epk, dinv, conv_b + 2 * HH, aggA, n);
    k_bnstats<<<1024, 256, 0, stream>>>(aggA, cs2, cq2, n);

    // ---- attention gemm (BN2 fused; res=h2(aggB); h3 -> aggA in place; GEMV+max epilogue) ----
    k_gemm<1, 1><<<256, 256, 0, stream>>>(aggA, aggA, aggB, cs2, cq2, bn_g + 2 * HH, bn_b + 2 * HH,
                                          attn_w1, attn_b1, apre, attn_w2, attn_b2, gmaxu, n);

    // ---- pooling (+ global exp-sum) + MLP ----
    k_pool<<<1024, 256, 0, stream>>>(aggA, apre, batch, gmaxu, pooled, counts, Sglob, n);
    k_mlp<<<GG, 128, 0, stream>>>(pooled, counts, Sglob, proj_w1, proj_b1, proj_w2, proj_b2,
                                  (float*)d_out);
}